// Round 7
// baseline (206.731 us; speedup 1.0000x reference)
//
#include <hip/hip_runtime.h>
#include <hip/hip_bf16.h>

// LSTM cell fused kernels for MI355X (gfx950).
// B=65536, H=256. R7: two-kernel split.
//  Kernel A: combine_bf16 = bf16(input+hidden) -> d_ws (streaming) + weight pack.
//  Kernel B: barrier-free, LDS-free GEMM+gates. Waves fully independent:
//            A-frags direct from combine_bf16 (L1/L2-hot 32KB row tile),
//            B-frags from packed weights, acc[4 gates][4 mf] = 64 regs.

typedef __attribute__((ext_vector_type(8))) short short8;   // 8 bf16
typedef __attribute__((ext_vector_type(4))) float f32x4;

static constexpr int Bsz   = 65536;
static constexpr int Hdim  = 256;
static constexpr int TROWS = 64;                   // rows per block
static constexpr size_t COMB_SHORTS = (size_t)Bsz * Hdim;        // 16.7M bf16
static constexpr size_t WS_NEED = COMB_SHORTS * 2 + 512 * 1024;  // 34 MB

// float -> bf16 bits, round-to-nearest-even
__device__ __forceinline__ short f2bf(float f) {
    unsigned u = __float_as_uint(f);
    return (short)((u + 0x7FFFu + ((u >> 16) & 1u)) >> 16);
}
__device__ __forceinline__ float sigm(float x) { return 1.0f / (1.0f + __expf(-x)); }
__device__ __forceinline__ float tanh_fast(float x) {
    return 2.0f / (1.0f + __expf(-2.0f * x)) - 1.0f;
}

// ---------------------------------------------------------------------------
// Kernel A. Blocks [0,1024): pack weights (verified R2/R5 layout):
//   flat o = (((g*8 + ks)*16 + jf)*64 + lane)*8 + e
//   k = ks*32 + (lane>>4)*8 + e ; j = jf*16 + (lane&15) ; B[k][j] = W_g[j][k]
// Blocks [1024,9216): combine_bf16[i] = bf16(input[i] + hidden[i]), 8/thread.
// ---------------------------------------------------------------------------
__global__ void __launch_bounds__(256)
prep_kernel(const float* __restrict__ inp, const float* __restrict__ hid,
            const float* __restrict__ Wf, const float* __restrict__ Wc,
            const float* __restrict__ Wi, const float* __restrict__ Wo,
            short* __restrict__ comb, short* __restrict__ Bp)
{
    int bid = blockIdx.x;
    if (bid < 1024) {
        int o    = bid * 256 + threadIdx.x;   // 0 .. 262143
        int e    = o & 7;
        int lane = (o >> 3) & 63;
        int jf   = (o >> 9) & 15;
        int ks   = (o >> 13) & 7;
        int g    = (o >> 16) & 3;
        int k = ks * 32 + (lane >> 4) * 8 + e;
        int j = jf * 16 + (lane & 15);
        const float* W = (g == 0) ? Wf : (g == 1) ? Wc : (g == 2) ? Wi : Wo;
        Bp[o] = f2bf(W[j * 256 + k]);
    } else {
        size_t i8 = (size_t)(bid - 1024) * 256 + threadIdx.x;  // short8 index
        const float4* ip = reinterpret_cast<const float4*>(inp + i8 * 8);
        const float4* hp = reinterpret_cast<const float4*>(hid + i8 * 8);
        float4 a0 = ip[0], a1 = ip[1];
        float4 h0 = hp[0], h1 = hp[1];
        short8 v;
        v[0] = f2bf(a0.x + h0.x);
        v[1] = f2bf(a0.y + h0.y);
        v[2] = f2bf(a0.z + h0.z);
        v[3] = f2bf(a0.w + h0.w);
        v[4] = f2bf(a1.x + h1.x);
        v[5] = f2bf(a1.y + h1.y);
        v[6] = f2bf(a1.z + h1.z);
        v[7] = f2bf(a1.w + h1.w);
        reinterpret_cast<short8*>(comb)[i8] = v;
    }
}

// ---------------------------------------------------------------------------
// Kernel B. 4096 blocks x 256 threads (4 waves). NO LDS, NO BARRIER.
// Block = 64 rows x 64 gate-cols (j-quarter) x 4 gates.
// Wave w owns j in [jbase + w*16, +16) for all 4 gates; 64 rows.
// XCD swizzle: the 4 j-siblings of a row-tile land on the same XCD.
// PRE: A-frags from precomputed combine_bf16; else from input+hidden.
// ---------------------------------------------------------------------------
template<bool PRE>
__global__ void __launch_bounds__(256, 4)
lstm_main(const short* __restrict__ comb,
          const float* __restrict__ inp, const float* __restrict__ hid,
          const float* __restrict__ cell, const short* __restrict__ Bp,
          const float* __restrict__ bfv, const float* __restrict__ bcv,
          const float* __restrict__ biv, const float* __restrict__ bov,
          float* __restrict__ out)
{
    const int tid  = threadIdx.x;
    const int lane = tid & 63;
    const int wave = tid >> 6;              // 0..3
    const int lm   = lane & 15;
    const int lk   = lane >> 4;

    // jq = (bid>>3)&3, rowtile = (bid>>5)*8 + (bid&7):
    // bids {b, b+8, b+16, b+24} (same XCD under %8 round-robin) are the four
    // j-quarters of one row-tile -> combine L2 reuse + store-line merging.
    const int bid     = blockIdx.x;
    const int jq      = (bid >> 3) & 3;
    const int rowtile = (bid >> 5) * 8 + (bid & 7);
    const int rowblk  = rowtile * TROWS;
    const int jbase   = jq * 64;

    const int j         = jbase + wave * 16 + lm;   // this lane's gate-col
    const int jf_global = jq * 4 + wave;            // j / 16

    // bias first (4 scalars, L2-hot)
    const float bF = bfv[j], bC = bcv[j], bI = biv[j], bO = bov[j];

    f32x4 acc[4][4];                     // [gate][mf] = 64 VGPRs
    acc[0][0] = (f32x4){bF, bF, bF, bF};
    acc[1][0] = (f32x4){bC, bC, bC, bC};
    acc[2][0] = (f32x4){bI, bI, bI, bI};
    acc[3][0] = (f32x4){bO, bO, bO, bO};
#pragma unroll
    for (int g = 0; g < 4; ++g)
#pragma unroll
        for (int mf = 1; mf < 4; ++mf)
            acc[g][mf] = acc[g][0];

    // ---- GEMM: K=256 in 8 steps; all operands straight from memory --------
#pragma unroll
    for (int ks = 0; ks < 8; ++ks) {
        short8 af[4];
#pragma unroll
        for (int mf = 0; mf < 4; ++mf) {
            int row = rowblk + mf * 16 + lm;
            if (PRE) {
                // 16B per lane; wave = 16 rows x 64B aligned segments (L1-hot)
                af[mf] = *reinterpret_cast<const short8*>(
                             comb + (size_t)row * Hdim + ks * 32 + lk * 8);
            } else {
                const float* ipr = inp + (size_t)row * Hdim + ks * 32 + lk * 8;
                const float* hpr = hid + (size_t)row * Hdim + ks * 32 + lk * 8;
                float4 a0 = *reinterpret_cast<const float4*>(ipr);
                float4 a1 = *reinterpret_cast<const float4*>(ipr + 4);
                float4 h0 = *reinterpret_cast<const float4*>(hpr);
                float4 h1 = *reinterpret_cast<const float4*>(hpr + 4);
                short8 v;
                v[0] = f2bf(a0.x + h0.x);
                v[1] = f2bf(a0.y + h0.y);
                v[2] = f2bf(a0.z + h0.z);
                v[3] = f2bf(a0.w + h0.w);
                v[4] = f2bf(a1.x + h1.x);
                v[5] = f2bf(a1.y + h1.y);
                v[6] = f2bf(a1.z + h1.z);
                v[7] = f2bf(a1.w + h1.w);
                af[mf] = v;
            }
        }
#pragma unroll
        for (int g = 0; g < 4; ++g) {
            int chunk = (g * 8 + ks) * 16 + jf_global;
            short8 b = *reinterpret_cast<const short8*>(
                           Bp + ((size_t)chunk * 64 + lane) * 8);   // 1KB/wave, contiguous
            acc[g][0] = __builtin_amdgcn_mfma_f32_16x16x32_bf16(af[0], b, acc[g][0], 0, 0, 0);
            acc[g][1] = __builtin_amdgcn_mfma_f32_16x16x32_bf16(af[1], b, acc[g][1], 0, 0, 0);
            acc[g][2] = __builtin_amdgcn_mfma_f32_16x16x32_bf16(af[2], b, acc[g][2], 0, 0, 0);
            acc[g][3] = __builtin_amdgcn_mfma_f32_16x16x32_bf16(af[3], b, acc[g][3], 0, 0, 0);
        }
    }

    // ---- cell loads (after GEMM: keeps reg peak low; 64B-coalesced) -------
    float cv[4][4];
#pragma unroll
    for (int mf = 0; mf < 4; ++mf)
#pragma unroll
        for (int r = 0; r < 4; ++r)
            cv[mf][r] = cell[(size_t)(rowblk + mf * 16 + lk * 4 + r) * Hdim + j];

    // ---- epilogue: gates + states, scalar fp32 stores (64B segments) ------
    float* out0 = out;                               // out gate
    float* out1 = out + (size_t)Bsz * Hdim;          // hidden_state
    float* out2 = out + (size_t)2 * Bsz * Hdim;      // cell_state

#pragma unroll
    for (int mf = 0; mf < 4; ++mf) {
#pragma unroll
        for (int r = 0; r < 4; ++r) {
            int row = rowblk + mf * 16 + lk * 4 + r;   // C/D: row=(lane>>4)*4+reg
            size_t off = (size_t)row * Hdim + j;
            float F = sigm(acc[0][mf][r]);
            float C = tanh_fast(acc[1][mf][r]);
            float I = sigm(sigm(acc[2][mf][r]));       // double sigmoid, per ref
            float O = sigm(acc[3][mf][r]);
            float cs = cv[mf][r] * F + C * I;
            float hs = O * tanh_fast(cs);
            out0[off] = O;
            out1[off] = hs;
            out2[off] = cs;
        }
    }
}

extern "C" void kernel_launch(void* const* d_in, const int* in_sizes, int n_in,
                              void* d_out, int out_size, void* d_ws, size_t ws_size,
                              hipStream_t stream)
{
    const float* inp  = (const float*)d_in[0];
    const float* hid  = (const float*)d_in[1];
    const float* cell = (const float*)d_in[2];
    const float* Wf   = (const float*)d_in[3];
    const float* bf_  = (const float*)d_in[4];
    const float* Wc   = (const float*)d_in[5];
    const float* bc_  = (const float*)d_in[6];
    const float* Wi   = (const float*)d_in[7];
    const float* bi_  = (const float*)d_in[8];
    const float* Wo   = (const float*)d_in[9];
    const float* bo_  = (const float*)d_in[10];
    float* outp = (float*)d_out;

    const int NBLK = (Bsz / TROWS) * 4;   // 4096

    if (ws_size >= WS_NEED) {
        short* comb = (short*)d_ws;                   // 32 MB combine_bf16
        short* Bp   = comb + COMB_SHORTS;             // 512 KB packed weights
        prep_kernel<<<1024 + Bsz * Hdim / (256 * 8), 256, 0, stream>>>(
            inp, hid, Wf, Wc, Wi, Wo, comb, Bp);
        lstm_main<true><<<NBLK, 256, 0, stream>>>(comb, inp, hid, cell, Bp,
                                                  bf_, bc_, bi_, bo_, outp);
    } else {
        short* Bp = (short*)d_ws;                     // weights only
        prep_kernel<<<1024, 256, 0, stream>>>(inp, hid, Wf, Wc, Wi, Wo, nullptr, Bp);
        lstm_main<false><<<NBLK, 256, 0, stream>>>(nullptr, inp, hid, cell, Bp,
                                                   bf_, bc_, bi_, bo_, outp);
    }
}

// Round 8
// 137.520 us; speedup vs baseline: 1.5033x; 1.5033x over previous
//
#include <hip/hip_runtime.h>
#include <hip/hip_bf16.h>

// LSTM cell fused kernel for MI355X (gfx950).
// B=65536, H=256. Packed GEMM [B,256]x[256,1024] bf16 MFMA + fused gates.
// R8: R5 base (best measured: 139us) + transposed epilogue. Gates computed in
//     native C-layout; results transposed via per-wave LDS scratch (overlaying
//     the dead As buffer) so each output array is stored as 4 coalesced
//     dwordx4 instrs/wave = complete 128B lines from a single wave.

typedef __attribute__((ext_vector_type(8))) short short8;   // 8 bf16
typedef __attribute__((ext_vector_type(4))) float f32x4;

static constexpr int Bsz   = 65536;
static constexpr int Hdim  = 256;
static constexpr int TROWS = 32;
static constexpr int NBLK  = (Bsz / TROWS) * 2;   // 4096 blocks (2 j-halves)

// per-wave transpose scratch: 32 rows x 32 cols, stride 35 floats (bank-safe)
static constexpr int SCR_STRIDE = 35;
static constexpr int SCR_BYTES  = 32 * SCR_STRIDE * 4;          // 4480 B
static constexpr int POOL_BYTES = (4 * SCR_BYTES > 16384) ? 4 * SCR_BYTES : 16384;

// float -> bf16 bits, round-to-nearest-even
__device__ __forceinline__ short f2bf(float f) {
    unsigned u = __float_as_uint(f);
    return (short)((u + 0x7FFFu + ((u >> 16) & 1u)) >> 16);
}
__device__ __forceinline__ float sigm(float x) { return 1.0f / (1.0f + __expf(-x)); }
__device__ __forceinline__ float tanh_fast(float x) {
    return 2.0f / (1.0f + __expf(-2.0f * x)) - 1.0f;
}

// ---------------------------------------------------------------------------
// Pack Wf,Wc,Wi,Wo ([256,256] fp32) into bf16 B-fragment-major layout for
// mfma_f32_16x16x32_bf16 (identical to R2/R5, verified):
//   flat o = (((g*8 + ks)*16 + jf)*64 + lane)*8 + e
//   k = ks*32 + (lane>>4)*8 + e ;  j = jf*16 + (lane&15) ;  B[k][j] = W_g[j][k]
// ---------------------------------------------------------------------------
__global__ void __launch_bounds__(256)
prep_w_kernel(const float* __restrict__ Wf, const float* __restrict__ Wc,
              const float* __restrict__ Wi, const float* __restrict__ Wo,
              short* __restrict__ Bp)
{
    int o    = blockIdx.x * 256 + threadIdx.x;   // 0 .. 262143
    int e    = o & 7;
    int lane = (o >> 3) & 63;
    int jf   = (o >> 9) & 15;
    int ks   = (o >> 13) & 7;
    int g    = (o >> 16) & 3;
    int k = ks * 32 + (lane >> 4) * 8 + e;
    int j = jf * 16 + (lane & 15);
    const float* W = (g == 0) ? Wf : (g == 1) ? Wc : (g == 2) ? Wi : Wo;
    Bp[o] = f2bf(W[j * 256 + k]);
}

// ---------------------------------------------------------------------------
// Main fused kernel. 4096 blocks x 256 threads (4 waves). Block handles
// 32 batch rows x one j-half (128 of 256 gate-cols) for all 4 gates.
// Wave w owns per-gate cols [jh*128 + w*32, +32). Two barriers per block.
// ---------------------------------------------------------------------------
__global__ void __launch_bounds__(256, 4)
lstm_fused(const float* __restrict__ inp, const float* __restrict__ hid,
           const float* __restrict__ cell, const short* __restrict__ Bp,
           const float* __restrict__ bfv, const float* __restrict__ bcv,
           const float* __restrict__ biv, const float* __restrict__ bov,
           float* __restrict__ out)
{
    // pool: combine tile (16 KB) during GEMM; 4x per-wave transpose scratch after
    __shared__ __align__(16) char pool[POOL_BYTES];
    __shared__ float Cs[TROWS * 132];       // 16.5 KB cell tile (+4 pad)
    __shared__ float Blds[4 * 128];         // 2 KB biases (this j-half)

    short* As = reinterpret_cast<short*>(pool);

    const int tid  = threadIdx.x;
    const int lane = tid & 63;
    const int wave = tid >> 6;
    const int lm   = lane & 15;
    const int lk   = lane >> 4;

    // XCD-paired swizzle: bids 16t+k and 16t+8+k (same XCD under %8
    // round-robin) are the two j-halves of the same row-tile.
    const int bid     = blockIdx.x;
    const int rowtile = (bid >> 4) * 8 + (bid & 7);
    const int jh      = (bid >> 3) & 1;
    const int rowblk  = rowtile * TROWS;
    const int jbase   = jh * 128;

    // ---- issue combine loads (4 chunks of 8 floats per thread) ------------
    float4 Li[4][2], Lh[4][2];
#pragma unroll
    for (int c = 0; c < 4; ++c) {
        int cc  = tid + c * 256;         // chunk 0..1023
        int row = cc >> 5;               // 0..31
        int k0  = (cc & 31) * 8;         // 0..248
        const float4* ip = reinterpret_cast<const float4*>(inp + (size_t)(rowblk + row) * Hdim + k0);
        const float4* hp = reinterpret_cast<const float4*>(hid + (size_t)(rowblk + row) * Hdim + k0);
        Li[c][0] = ip[0]; Li[c][1] = ip[1];
        Lh[c][0] = hp[0]; Lh[c][1] = hp[1];
    }
    // ---- issue cell loads (this j-half: 32x128 floats) --------------------
    float4 Lc[4];
#pragma unroll
    for (int c = 0; c < 4; ++c) {
        int flat = c * 1024 + tid * 4;   // float index in 32x128 tile
        int row  = flat >> 7;
        int col  = flat & 127;
        Lc[c] = *reinterpret_cast<const float4*>(
                    cell + (size_t)(rowblk + row) * Hdim + jbase + col);
    }
    // ---- biases for this j-half ------------------------------------------
    if (tid < 128) {
        int g  = tid >> 5;
        int j4 = (tid & 31) * 4;
        const float* bp = (g == 0) ? bfv : (g == 1) ? bcv : (g == 2) ? biv : bov;
        *reinterpret_cast<float4*>(&Blds[g * 128 + j4]) =
            *reinterpret_cast<const float4*>(bp + jbase + j4);
    }

    // ---- pack combine -> As (bf16, XOR swizzle) ---------------------------
#pragma unroll
    for (int c = 0; c < 4; ++c) {
        int cc  = tid + c * 256;
        int row = cc >> 5;
        int k0  = (cc & 31) * 8;
        short8 v;
        v[0] = f2bf(Li[c][0].x + Lh[c][0].x);
        v[1] = f2bf(Li[c][0].y + Lh[c][0].y);
        v[2] = f2bf(Li[c][0].z + Lh[c][0].z);
        v[3] = f2bf(Li[c][0].w + Lh[c][0].w);
        v[4] = f2bf(Li[c][1].x + Lh[c][1].x);
        v[5] = f2bf(Li[c][1].y + Lh[c][1].y);
        v[6] = f2bf(Li[c][1].z + Lh[c][1].z);
        v[7] = f2bf(Li[c][1].w + Lh[c][1].w);
        int byte = row * 512 + k0 * 2;
        byte ^= (row & 7) << 4;
        *reinterpret_cast<short8*>(reinterpret_cast<char*>(As) + byte) = v;
    }
    // ---- cell -> Cs -------------------------------------------------------
#pragma unroll
    for (int c = 0; c < 4; ++c) {
        int flat = c * 1024 + tid * 4;
        int row  = flat >> 7;
        int col  = flat & 127;
        *reinterpret_cast<float4*>(&Cs[row * 132 + col]) = Lc[c];
    }

    __syncthreads();    // As, Cs, Blds all visible; staging loads drained

    // ---- acc init = bias --------------------------------------------------
    f32x4 acc[4][2][2];                  // [gate][mf(rows)][jf]
#pragma unroll
    for (int g = 0; g < 4; ++g)
#pragma unroll
        for (int jf = 0; jf < 2; ++jf) {
            float b = Blds[g * 128 + wave * 32 + jf * 16 + lm];
            f32x4 bb = (f32x4){b, b, b, b};
            acc[g][0][jf] = bb;
            acc[g][1][jf] = bb;
        }

    // ---- GEMM: K=256 in 8 steps ------------------------------------------
    const char* A = reinterpret_cast<const char*>(As);
#pragma unroll
    for (int ks = 0; ks < 8; ++ks) {
        short8 cf[2];
#pragma unroll
        for (int mf = 0; mf < 2; ++mf) {
            int row  = mf * 16 + lm;
            int byte = row * 512 + (ks * 32 + lk * 8) * 2;
            byte ^= (row & 7) << 4;
            cf[mf] = *reinterpret_cast<const short8*>(A + byte);
        }
#pragma unroll
        for (int g = 0; g < 4; ++g)
#pragma unroll
            for (int jf = 0; jf < 2; ++jf) {
                int chunk = (g * 8 + ks) * 16 + jh * 8 + wave * 2 + jf;
                short8 b = *reinterpret_cast<const short8*>(
                               Bp + ((size_t)chunk * 64 + lane) * 8);
                acc[g][0][jf] = __builtin_amdgcn_mfma_f32_16x16x32_bf16(cf[0], b, acc[g][0][jf], 0, 0, 0);
                acc[g][1][jf] = __builtin_amdgcn_mfma_f32_16x16x32_bf16(cf[1], b, acc[g][1][jf], 0, 0, 0);
            }
    }

    // ---- gates in native C-layout (cell from LDS) -------------------------
    f32x4 ov[2][2], hv[2][2], csv[2][2];             // [mf][jf]
#pragma unroll
    for (int mf = 0; mf < 2; ++mf)
#pragma unroll
        for (int jf = 0; jf < 2; ++jf) {
            int jloc = wave * 32 + jf * 16 + lm;
#pragma unroll
            for (int r = 0; r < 4; ++r) {
                int rloc = mf * 16 + lk * 4 + r;
                float cvv = Cs[rloc * 132 + jloc];
                float F = sigm(acc[0][mf][jf][r]);
                float C = tanh_fast(acc[1][mf][jf][r]);
                float I = sigm(sigm(acc[2][mf][jf][r]));   // double sigmoid, per ref
                float O = sigm(acc[3][mf][jf][r]);
                float cs = cvv * F + C * I;
                ov[mf][jf][r]  = O;
                hv[mf][jf][r]  = O * tanh_fast(cs);
                csv[mf][jf][r] = cs;
            }
        }

    __syncthreads();    // all waves done reading As -> pool becomes scratch

    // ---- transposed stores via per-wave scratch ---------------------------
    float* scr = reinterpret_cast<float*>(pool + wave * SCR_BYTES);
    float* outs[3] = { out,                                // out gate
                       out + (size_t)Bsz * Hdim,           // hidden_state
                       out + (size_t)2 * Bsz * Hdim };     // cell_state

    const int row_t = (lane >> 3);        // +8*v
    const int q_t   = lane & 7;

#pragma unroll
    for (int x = 0; x < 3; ++x) {
        // scatter this wave's 32x32 tile into scratch (native layout)
#pragma unroll
        for (int mf = 0; mf < 2; ++mf)
#pragma unroll
            for (int jf = 0; jf < 2; ++jf)
#pragma unroll
                for (int r = 0; r < 4; ++r) {
                    int rloc = mf * 16 + lk * 4 + r;
                    int jloc = jf * 16 + lm;
                    f32x4 src = (x == 0) ? ov[mf][jf] : (x == 1) ? hv[mf][jf] : csv[mf][jf];
                    scr[rloc * SCR_STRIDE + jloc] = src[r];
                }
        asm volatile("s_waitcnt lgkmcnt(0)" ::: "memory");
        __builtin_amdgcn_sched_barrier(0);
        // gather transposed: lane -> (row_t+8v, 4 consecutive j) float4
#pragma unroll
        for (int v = 0; v < 4; ++v) {
            int rr = v * 8 + row_t;
            f32x4 t = *reinterpret_cast<const f32x4*>(&scr[rr * SCR_STRIDE + q_t * 4]);
            size_t off = (size_t)(rowblk + rr) * Hdim + jbase + wave * 32 + q_t * 4;
            *reinterpret_cast<f32x4*>(outs[x] + off) = t;
        }
        asm volatile("s_waitcnt lgkmcnt(0)" ::: "memory");
        __builtin_amdgcn_sched_barrier(0);
    }
}

extern "C" void kernel_launch(void* const* d_in, const int* in_sizes, int n_in,
                              void* d_out, int out_size, void* d_ws, size_t ws_size,
                              hipStream_t stream)
{
    const float* inp  = (const float*)d_in[0];
    const float* hid  = (const float*)d_in[1];
    const float* cell = (const float*)d_in[2];
    const float* Wf   = (const float*)d_in[3];
    const float* bf_  = (const float*)d_in[4];
    const float* Wc   = (const float*)d_in[5];
    const float* bc_  = (const float*)d_in[6];
    const float* Wi   = (const float*)d_in[7];
    const float* bi_  = (const float*)d_in[8];
    const float* Wo   = (const float*)d_in[9];
    const float* bo_  = (const float*)d_in[10];

    short* Bp = (short*)d_ws;    // 512 KB packed bf16 weights

    prep_w_kernel<<<1024, 256, 0, stream>>>(Wf, Wc, Wi, Wo, Bp);
    lstm_fused<<<NBLK, 256, 0, stream>>>(inp, hid, cell, Bp,
                                         bf_, bc_, bi_, bo_, (float*)d_out);
}